// Round 7
// baseline (104.637 us; speedup 1.0000x reference)
//
#include <hip/hip_runtime.h>
#include <stdint.h>

#define CCH 32
#define BATCH 512
#define NROW 1024   // 2*BATCH
#define DDIM 768
#define TILE 128
#define NPAIRS 36   // upper-tri tile pairs of 8x8
#define BK 32
#define NSTEP (DDIM / BK)   // 24

typedef unsigned short u16;
typedef __attribute__((ext_vector_type(8))) short short8v;   // 8 bf16 (4 VGPRs)
typedef __attribute__((ext_vector_type(4))) float f32x4;     // MFMA acc

__device__ __forceinline__ u16 f2bf_rne(float x) {
    uint32_t u = __float_as_uint(x);
    u += 0x7FFFu + ((u >> 16) & 1u);
    return (u16)(u >> 16);
}
__device__ __forceinline__ float bf2f(u16 h) {
    return __uint_as_float(((uint32_t)h) << 16);
}

__device__ __forceinline__ void gload_lds16(const u16* g, u16* l) {
    // async global->LDS, 16B per lane; LDS dest = wave-uniform base + lane*16
    __builtin_amdgcn_global_load_lds(
        (const __attribute__((address_space(1))) unsigned int*)(g),
        (__attribute__((address_space(3))) unsigned int*)(l),
        16, 0, 0);
}

__constant__ int PI_[NPAIRS] = {0,0,0,0,0,0,0,0, 1,1,1,1,1,1,1, 2,2,2,2,2,2,
                                3,3,3,3,3, 4,4,4,4, 5,5,5, 6,6, 7};
__constant__ int PJ_[NPAIRS] = {0,1,2,3,4,5,6,7, 1,2,3,4,5,6,7, 2,3,4,5,6,7,
                                3,4,5,6,7, 4,5,6,7, 5,6,7, 6,7, 7};

// ---------------- prep: fp32 -> bf16 row-major + row norms; 4 rows/wave (MLP=12) -----
__global__ __launch_bounds__(256) void k_prep(const float* __restrict__ src,
                                              const float* __restrict__ tgt,
                                              u16* __restrict__ bfbuf,
                                              float* __restrict__ sq) {
    int wid = threadIdx.x >> 6, lane = threadIdx.x & 63;
    int rbase = blockIdx.x * 16 + wid * 4;   // 4 rows per wave; grid 2048
    const float* rp[4];
#pragma unroll
    for (int r = 0; r < 4; ++r) {
        int row = rbase + r;
        int c = row >> 10, i = row & 1023;
        rp[r] = (i < BATCH) ? (src + ((size_t)i * CCH + c) * DDIM)
                            : (tgt + ((size_t)(i - BATCH) * CCH + c) * DDIM);
    }
    float4 v[4][3];
#pragma unroll
    for (int r = 0; r < 4; ++r)
#pragma unroll
        for (int j = 0; j < 3; ++j)
            v[r][j] = *(reinterpret_cast<const float4*>(rp[r]) + lane + j * 64);
    // 12 independent loads in flight before first use
#pragma unroll
    for (int r = 0; r < 4; ++r) {
        u16* orow = bfbuf + (size_t)(rbase + r) * DDIM;
        float ss = 0.f;
#pragma unroll
        for (int j = 0; j < 3; ++j) {
            float4 w = v[r][j];
            u16 h0 = f2bf_rne(w.x), h1 = f2bf_rne(w.y), h2 = f2bf_rne(w.z), h3 = f2bf_rne(w.w);
            float f0 = bf2f(h0), f1 = bf2f(h1), f2 = bf2f(h2), f3 = bf2f(h3);
            ss += f0 * f0 + f1 * f1 + f2 * f2 + f3 * f3;
            ushort4 hv; hv.x = h0; hv.y = h1; hv.z = h2; hv.w = h3;
            *reinterpret_cast<ushort4*>(orow + (size_t)(lane + j * 64) * 4) = hv;
        }
#pragma unroll
        for (int off = 32; off > 0; off >>= 1) ss += __shfl_down(ss, off);
        if (lane == 0) sq[rbase + r] = ss;
    }
}

// ---------------- partial column sums over 128-row chunks (R2, proven) ---------------
__global__ __launch_bounds__(256) void k_colsum(const u16* __restrict__ bfbuf,
                                                float* __restrict__ colpart) {
    int c = blockIdx.x >> 3, ic = blockIdx.x & 7;
    const u16* base = bfbuf + ((size_t)c * NROW + (size_t)ic * 128) * DDIM;
#pragma unroll
    for (int j = 0; j < 3; ++j) {
        int d = threadIdx.x + j * 256;
        float s0 = 0.f, s1 = 0.f;
        for (int r = 0; r < 128; r += 2) {
            s0 += bf2f(base[(size_t)r * DDIM + d]);
            s1 += bf2f(base[(size_t)(r + 1) * DDIM + d]);
        }
        colpart[((size_t)c * 8 + ic) * DDIM + d] = s0 + s1;
    }
}

// ---------------- bandwidth: sum(d2) = 2n*sum(sq) - 2*||colsum||^2 -------------------
__global__ __launch_bounds__(256) void k_bw(const float* __restrict__ sq,
                                            const float* __restrict__ colpart,
                                            float* __restrict__ bwc) {
    int c = blockIdx.x, t = threadIdx.x;
    const float* sqc = sq + (size_t)c * NROW;
    float s = sqc[t] + sqc[t + 256] + sqc[t + 512] + sqc[t + 768];
    float s2 = 0.f;
#pragma unroll
    for (int j = 0; j < 3; ++j) {
        int d = t + j * 256;
        float cs = 0.f;
#pragma unroll
        for (int ic = 0; ic < 8; ++ic) cs += colpart[((size_t)c * 8 + ic) * DDIM + d];
        s2 += cs * cs;
    }
    __shared__ float redA[256], redB[256];
    redA[t] = s; redB[t] = s2;
    __syncthreads();
    for (int k = 128; k > 0; k >>= 1) {
        if (t < k) { redA[t] += redA[t + k]; redB[t] += redB[t + k]; }
        __syncthreads();
    }
    if (t == 0) {
        double sumd2 = 2.0 * (double)NROW * (double)redA[0] - 2.0 * (double)redB[0];
        double bw = sumd2 / ((double)NROW * (double)NROW - (double)NROW) / 4.0; // /2^(5//2)
        bwc[c] = (float)(-1.4426950408889634 / (16.0 * bw));  // exp2 scale, largest bw
    }
}

// ---------------- main: 2-buffer (32KB), 5 blocks/CU, unrolled counted-vmcnt loop ----
__global__ __launch_bounds__(256, 5) void k_mmd(const u16* __restrict__ bfbuf,
                                                const float* __restrict__ sq,
                                                const float* __restrict__ bwc,
                                                float* __restrict__ partial) {
    // bijective XCD swizzle: 1152 = 8 * 144 (4 channels contiguous per XCD)
    int orig = blockIdx.x;
    int blk = (orig & 7) * 144 + (orig >> 3);
    int c = blk / NPAIRS, p = blk - c * NPAIRS;
    int ti = PI_[p], tj = PJ_[p];
    const u16* Ab = bfbuf + ((size_t)c * NROW + (size_t)ti * TILE) * DDIM;
    const u16* Bb = bfbuf + ((size_t)c * NROW + (size_t)tj * TILE) * DDIM;

    __shared__ __align__(16) u16 lA[2][TILE * BK];   // 2 x 8 KB
    __shared__ __align__(16) u16 lB[2][TILE * BK];   // 2 x 8 KB  = 32768 B exactly

    int t = threadIdx.x;
    int wid = t >> 6, lane = t & 63;
    int lr = lane & 15, kg = lane >> 4;
    int wr = wid >> 1, wc = wid & 1;              // 2x2 wave grid; wave owns 64x64

    // per-lane invariant staging geometry (hoisted):
    int g0 = t, row0 = g0 >> 2, kc0 = ((g0 & 3) ^ ((row0 >> 1) & 3)) * 8;
    int g1 = t + 256, row1 = g1 >> 2, kc1 = ((g1 & 3) ^ ((row1 >> 1) & 3)) * 8;
    const u16* gA0 = Ab + (size_t)row0 * DDIM + kc0;
    const u16* gA1 = Ab + (size_t)row1 * DDIM + kc1;
    const u16* gB0 = Bb + (size_t)row0 * DDIM + kc0;
    const u16* gB1 = Bb + (size_t)row1 * DDIM + kc1;

    auto STAGE = [&](int buf, int k0) {
        gload_lds16(gA0 + k0, &lA[buf][(size_t)(wid * 64) * 8]);
        gload_lds16(gB0 + k0, &lB[buf][(size_t)(wid * 64) * 8]);
        gload_lds16(gA1 + k0, &lA[buf][(size_t)(wid * 64 + 256) * 8]);
        gload_lds16(gB1 + k0, &lB[buf][(size_t)(wid * 64 + 256) * 8]);
    };

    f32x4 acc[4][4];
#pragma unroll
    for (int m = 0; m < 4; ++m)
#pragma unroll
        for (int n = 0; n < 4; ++n) acc[m][n] = f32x4{0.f, 0.f, 0.f, 0.f};

    // swizzled read slot (proven 0-conflict): depends only on lr
    int ks = (kg ^ ((lr >> 1) & 3)) * 8;
    int raddrA = (wr * 64 + lr) * BK + ks;        // + m*16*BK
    int raddrB = (wc * 64 + lr) * BK + ks;        // + n*16*BK

    STAGE(0, 0);                                  // prologue: 4 loads in flight

#pragma unroll
    for (int s = 0; s < NSTEP; ++s) {
        if (s + 1 < NSTEP) {
            STAGE((s + 1) & 1, (s + 1) * BK);     // buf^1 free: certified by barrier#2(s-1)
            asm volatile("s_waitcnt vmcnt(4)" ::: "memory");  // drain stage(s); keep stage(s+1)
        } else {
            asm volatile("s_waitcnt vmcnt(0)" ::: "memory");
        }
        asm volatile("s_barrier" ::: "memory");   // #1: tile s resident for all waves

        const int cur = s & 1;                    // compile-time after unroll
        short8v af[4], bf[4];
#pragma unroll
        for (int m = 0; m < 4; ++m)
            af[m] = *reinterpret_cast<const short8v*>(&lA[cur][raddrA + m * 16 * BK]);
#pragma unroll
        for (int n = 0; n < 4; ++n)
            bf[n] = *reinterpret_cast<const short8v*>(&lB[cur][raddrB + n * 16 * BK]);
#pragma unroll
        for (int m = 0; m < 4; ++m)
#pragma unroll
            for (int n = 0; n < 4; ++n)
                acc[m][n] = __builtin_amdgcn_mfma_f32_16x16x32_bf16(af[m], bf[n], acc[m][n], 0, 0, 0);

        asm volatile("s_barrier" ::: "memory");   // #2: all reads of buf_s done
    }

    // epilogue: d2 -> sum_k exp(-d2/bw_k) via t + t^2 + t^4 + t^8 + t^16
    float ci = bwc[c];                            // -log2(e)/(16*bw)
    const float* sqc = sq + (size_t)c * NROW;
    float sqi[4][4], sqj[4];
#pragma unroll
    for (int m = 0; m < 4; ++m) {
        float4 s4 = *reinterpret_cast<const float4*>(&sqc[ti * TILE + wr * 64 + m * 16 + kg * 4]);
        sqi[m][0] = s4.x; sqi[m][1] = s4.y; sqi[m][2] = s4.z; sqi[m][3] = s4.w;
    }
#pragma unroll
    for (int n = 0; n < 4; ++n)
        sqj[n] = sqc[tj * TILE + wc * 64 + n * 16 + lr];

    float psum = 0.f;
#pragma unroll
    for (int m = 0; m < 4; ++m)
#pragma unroll
        for (int n = 0; n < 4; ++n) {
#pragma unroll
            for (int r = 0; r < 4; ++r) {
                // C/D layout (m89-verified): col = lane&15, row = (lane>>4)*4 + r
                float d2 = sqi[m][r] + sqj[n] - 2.0f * acc[m][n][r];
                float t1 = __builtin_amdgcn_exp2f(d2 * ci);
                float t2 = t1 * t1, t4 = t2 * t2, t8 = t4 * t4, t16 = t8 * t8;
                psum += ((t1 + t2) + (t4 + t8)) + t16;
            }
        }

#pragma unroll
    for (int off = 32; off > 0; off >>= 1) psum += __shfl_down(psum, off);
    float* red = reinterpret_cast<float*>(&lA[0][0]);
    __syncthreads();                              // all LDS reads done before reuse
    if (lane == 0) red[wid] = psum;
    __syncthreads();
    if (t == 0) {
        float sblk = red[0] + red[1] + red[2] + red[3];
        partial[blk] = sblk;
    }
}

// ---------------- final: deterministic combine of 32x36 tile sums --------------------
__global__ __launch_bounds__(64) void k_final(const float* __restrict__ partial,
                                              float* __restrict__ out) {
    int lane = threadIdx.x;
    double r = 0.0;
    if (lane < CCH) {
        const float* pp = partial + (size_t)lane * NPAIRS;
        double s = 0.0;
        for (int q = 0; q < NPAIRS; ++q) {
            int ti = PI_[q], tj = PJ_[q];
            double w = (ti == tj) ? 1.0 : 2.0;               // off-diag pair counted twice
            double sgn = ((ti < 4) == (tj < 4)) ? 1.0 : -1.0; // XX/YY : +, cross : -
            s += sgn * w * (double)pp[q];
        }
        r = s / ((double)BATCH * (double)BATCH);
    }
    for (int off = 16; off > 0; off >>= 1) r += __shfl_down(r, off);
    if (lane == 0) out[0] = (float)(r / (double)CCH);
}

extern "C" void kernel_launch(void* const* d_in, const int* in_sizes, int n_in,
                              void* d_out, int out_size, void* d_ws, size_t ws_size,
                              hipStream_t stream) {
    const float* src = (const float*)d_in[0];
    const float* tgt = (const float*)d_in[1];
    float* out = (float*)d_out;
    char* ws = (char*)d_ws;

    const size_t OFF_BF   = 0;                                       // 50,331,648 B
    const size_t OFF_SQ   = (size_t)CCH * NROW * DDIM * 2;           // +131,072 B
    const size_t OFF_CP   = OFF_SQ + (size_t)CCH * NROW * 4;         // +786,432 B
    const size_t OFF_BWC  = OFF_CP + (size_t)CCH * 8 * DDIM * 4;     // +128 B
    const size_t OFF_PART = OFF_BWC + (size_t)CCH * 4;               // +4,608 B

    u16*   bfbuf   = (u16*)(ws + OFF_BF);
    float* sq      = (float*)(ws + OFF_SQ);
    float* colpart = (float*)(ws + OFF_CP);
    float* bwc     = (float*)(ws + OFF_BWC);
    float* partial = (float*)(ws + OFF_PART);

    k_prep<<<CCH * NROW / 16, 256, 0, stream>>>(src, tgt, bfbuf, sq);
    k_colsum<<<CCH * 8, 256, 0, stream>>>(bfbuf, colpart);
    k_bw<<<CCH, 256, 0, stream>>>(sq, colpart, bwc);
    k_mmd<<<CCH * NPAIRS, 256, 0, stream>>>(bfbuf, sq, bwc, partial);
    k_final<<<1, 64, 0, stream>>>(partial, out);
}

// Round 8
// 89.406 us; speedup vs baseline: 1.1704x; 1.1704x over previous
//
#include <hip/hip_runtime.h>
#include <stdint.h>

#define CCH 32
#define BATCH 512
#define NROW 1024   // 2*BATCH
#define DDIM 768
#define TILE 128
#define NPAIRS 36   // upper-tri tile pairs of 8x8
#define BK 32
#define NSTEP (DDIM / BK)   // 24

typedef unsigned short u16;
typedef __attribute__((ext_vector_type(8))) short short8v;   // 8 bf16 (4 VGPRs)
typedef __attribute__((ext_vector_type(4))) float f32x4;     // MFMA acc

__device__ __forceinline__ u16 f2bf_rne(float x) {
    uint32_t u = __float_as_uint(x);
    u += 0x7FFFu + ((u >> 16) & 1u);
    return (u16)(u >> 16);
}
__device__ __forceinline__ float bf2f(u16 h) {
    return __uint_as_float(((uint32_t)h) << 16);
}

__device__ __forceinline__ void gload_lds16(const u16* g, u16* l) {
    // async global->LDS, 16B per lane; LDS dest = wave-uniform base + lane*16
    __builtin_amdgcn_global_load_lds(
        (const __attribute__((address_space(1))) unsigned int*)(g),
        (__attribute__((address_space(3))) unsigned int*)(l),
        16, 0, 0);
}

__constant__ int PI_[NPAIRS] = {0,0,0,0,0,0,0,0, 1,1,1,1,1,1,1, 2,2,2,2,2,2,
                                3,3,3,3,3, 4,4,4,4, 5,5,5, 6,6, 7};
__constant__ int PJ_[NPAIRS] = {0,1,2,3,4,5,6,7, 1,2,3,4,5,6,7, 2,3,4,5,6,7,
                                3,4,5,6,7, 4,5,6,7, 5,6,7, 6,7, 7};

// ---------------- prep: fp32 -> bf16 row-major + row norms; 4 rows/wave (MLP=12) -----
__global__ __launch_bounds__(256) void k_prep(const float* __restrict__ src,
                                              const float* __restrict__ tgt,
                                              u16* __restrict__ bfbuf,
                                              float* __restrict__ sq) {
    int wid = threadIdx.x >> 6, lane = threadIdx.x & 63;
    int rbase = blockIdx.x * 16 + wid * 4;   // 4 rows per wave; grid 2048
    const float* rp[4];
#pragma unroll
    for (int r = 0; r < 4; ++r) {
        int row = rbase + r;
        int c = row >> 10, i = row & 1023;
        rp[r] = (i < BATCH) ? (src + ((size_t)i * CCH + c) * DDIM)
                            : (tgt + ((size_t)(i - BATCH) * CCH + c) * DDIM);
    }
    float4 v[4][3];
#pragma unroll
    for (int r = 0; r < 4; ++r)
#pragma unroll
        for (int j = 0; j < 3; ++j)
            v[r][j] = *(reinterpret_cast<const float4*>(rp[r]) + lane + j * 64);
    // 12 independent loads in flight before first use
#pragma unroll
    for (int r = 0; r < 4; ++r) {
        u16* orow = bfbuf + (size_t)(rbase + r) * DDIM;
        float ss = 0.f;
#pragma unroll
        for (int j = 0; j < 3; ++j) {
            float4 w = v[r][j];
            u16 h0 = f2bf_rne(w.x), h1 = f2bf_rne(w.y), h2 = f2bf_rne(w.z), h3 = f2bf_rne(w.w);
            float f0 = bf2f(h0), f1 = bf2f(h1), f2 = bf2f(h2), f3 = bf2f(h3);
            ss += f0 * f0 + f1 * f1 + f2 * f2 + f3 * f3;
            ushort4 hv; hv.x = h0; hv.y = h1; hv.z = h2; hv.w = h3;
            *reinterpret_cast<ushort4*>(orow + (size_t)(lane + j * 64) * 4) = hv;
        }
#pragma unroll
        for (int off = 32; off > 0; off >>= 1) ss += __shfl_down(ss, off);
        if (lane == 0) sq[rbase + r] = ss;
    }
}

// ---------------- partial column sums over 128-row chunks (R2, proven) ---------------
__global__ __launch_bounds__(256) void k_colsum(const u16* __restrict__ bfbuf,
                                                float* __restrict__ colpart) {
    int c = blockIdx.x >> 3, ic = blockIdx.x & 7;
    const u16* base = bfbuf + ((size_t)c * NROW + (size_t)ic * 128) * DDIM;
#pragma unroll
    for (int j = 0; j < 3; ++j) {
        int d = threadIdx.x + j * 256;
        float s0 = 0.f, s1 = 0.f;
        for (int r = 0; r < 128; r += 2) {
            s0 += bf2f(base[(size_t)r * DDIM + d]);
            s1 += bf2f(base[(size_t)(r + 1) * DDIM + d]);
        }
        colpart[((size_t)c * 8 + ic) * DDIM + d] = s0 + s1;
    }
}

// ---------------- bandwidth: sum(d2) = 2n*sum(sq) - 2*||colsum||^2 -------------------
__global__ __launch_bounds__(256) void k_bw(const float* __restrict__ sq,
                                            const float* __restrict__ colpart,
                                            float* __restrict__ bwc) {
    int c = blockIdx.x, t = threadIdx.x;
    const float* sqc = sq + (size_t)c * NROW;
    float s = sqc[t] + sqc[t + 256] + sqc[t + 512] + sqc[t + 768];
    float s2 = 0.f;
#pragma unroll
    for (int j = 0; j < 3; ++j) {
        int d = t + j * 256;
        float cs = 0.f;
#pragma unroll
        for (int ic = 0; ic < 8; ++ic) cs += colpart[((size_t)c * 8 + ic) * DDIM + d];
        s2 += cs * cs;
    }
    __shared__ float redA[256], redB[256];
    redA[t] = s; redB[t] = s2;
    __syncthreads();
    for (int k = 128; k > 0; k >>= 1) {
        if (t < k) { redA[t] += redA[t + k]; redB[t] += redB[t + k]; }
        __syncthreads();
    }
    if (t == 0) {
        double sumd2 = 2.0 * (double)NROW * (double)redA[0] - 2.0 * (double)redB[0];
        double bw = sumd2 / ((double)NROW * (double)NROW - (double)NROW) / 4.0; // /2^(5//2)
        bwc[c] = (float)(-1.4426950408889634 / (16.0 * bw));  // exp2 scale, largest bw
    }
}

// ---------------- main: 2-buffer (32KB), VGPR-safe bounds, unrolled counted-vmcnt ----
// __launch_bounds__(256, 4): VGPR cap 128 (no spill; kernel needs ~68). Runtime
// residency is min(LDS 160/32=5, VGPR 512/68=7) = 5 blocks/CU -> 1280 slots >= 1152,
// whole grid co-resident in one round.
__global__ __launch_bounds__(256, 4) void k_mmd(const u16* __restrict__ bfbuf,
                                                const float* __restrict__ sq,
                                                const float* __restrict__ bwc,
                                                float* __restrict__ partial) {
    // bijective XCD swizzle: 1152 = 8 * 144 (4 channels contiguous per XCD)
    int orig = blockIdx.x;
    int blk = (orig & 7) * 144 + (orig >> 3);
    int c = blk / NPAIRS, p = blk - c * NPAIRS;
    int ti = PI_[p], tj = PJ_[p];
    const u16* Ab = bfbuf + ((size_t)c * NROW + (size_t)ti * TILE) * DDIM;
    const u16* Bb = bfbuf + ((size_t)c * NROW + (size_t)tj * TILE) * DDIM;

    __shared__ __align__(16) u16 lA[2][TILE * BK];   // 2 x 8 KB
    __shared__ __align__(16) u16 lB[2][TILE * BK];   // 2 x 8 KB  = 32768 B exactly

    int t = threadIdx.x;
    int wid = t >> 6, lane = t & 63;
    int lr = lane & 15, kg = lane >> 4;
    int wr = wid >> 1, wc = wid & 1;              // 2x2 wave grid; wave owns 64x64

    // per-lane invariant staging geometry (hoisted):
    int g0 = t, row0 = g0 >> 2, kc0 = ((g0 & 3) ^ ((row0 >> 1) & 3)) * 8;
    int g1 = t + 256, row1 = g1 >> 2, kc1 = ((g1 & 3) ^ ((row1 >> 1) & 3)) * 8;
    const u16* gA0 = Ab + (size_t)row0 * DDIM + kc0;
    const u16* gA1 = Ab + (size_t)row1 * DDIM + kc1;
    const u16* gB0 = Bb + (size_t)row0 * DDIM + kc0;
    const u16* gB1 = Bb + (size_t)row1 * DDIM + kc1;

    auto STAGE = [&](int buf, int k0) {
        gload_lds16(gA0 + k0, &lA[buf][(size_t)(wid * 64) * 8]);
        gload_lds16(gB0 + k0, &lB[buf][(size_t)(wid * 64) * 8]);
        gload_lds16(gA1 + k0, &lA[buf][(size_t)(wid * 64 + 256) * 8]);
        gload_lds16(gB1 + k0, &lB[buf][(size_t)(wid * 64 + 256) * 8]);
    };

    f32x4 acc[4][4];
#pragma unroll
    for (int m = 0; m < 4; ++m)
#pragma unroll
        for (int n = 0; n < 4; ++n) acc[m][n] = f32x4{0.f, 0.f, 0.f, 0.f};

    // swizzled read slot (proven 0-conflict): depends only on lr
    int ks = (kg ^ ((lr >> 1) & 3)) * 8;
    int raddrA = (wr * 64 + lr) * BK + ks;        // + m*16*BK
    int raddrB = (wc * 64 + lr) * BK + ks;        // + n*16*BK

    STAGE(0, 0);                                  // prologue: 4 loads in flight

#pragma unroll
    for (int s = 0; s < NSTEP; ++s) {
        if (s + 1 < NSTEP) {
            STAGE((s + 1) & 1, (s + 1) * BK);     // buf^1 free: certified by barrier#2(s-1)
            asm volatile("s_waitcnt vmcnt(4)" ::: "memory");  // drain stage(s); keep stage(s+1)
        } else {
            asm volatile("s_waitcnt vmcnt(0)" ::: "memory");
        }
        asm volatile("s_barrier" ::: "memory");   // #1: tile s resident for all waves

        const int cur = s & 1;                    // compile-time after unroll
        short8v af[4], bf[4];
#pragma unroll
        for (int m = 0; m < 4; ++m)
            af[m] = *reinterpret_cast<const short8v*>(&lA[cur][raddrA + m * 16 * BK]);
#pragma unroll
        for (int n = 0; n < 4; ++n)
            bf[n] = *reinterpret_cast<const short8v*>(&lB[cur][raddrB + n * 16 * BK]);
#pragma unroll
        for (int m = 0; m < 4; ++m)
#pragma unroll
            for (int n = 0; n < 4; ++n)
                acc[m][n] = __builtin_amdgcn_mfma_f32_16x16x32_bf16(af[m], bf[n], acc[m][n], 0, 0, 0);

        asm volatile("s_barrier" ::: "memory");   // #2: all reads of buf_s done
    }

    // epilogue: d2 -> sum_k exp(-d2/bw_k) via t + t^2 + t^4 + t^8 + t^16
    float ci = bwc[c];                            // -log2(e)/(16*bw)
    const float* sqc = sq + (size_t)c * NROW;
    float sqi[4][4], sqj[4];
#pragma unroll
    for (int m = 0; m < 4; ++m) {
        float4 s4 = *reinterpret_cast<const float4*>(&sqc[ti * TILE + wr * 64 + m * 16 + kg * 4]);
        sqi[m][0] = s4.x; sqi[m][1] = s4.y; sqi[m][2] = s4.z; sqi[m][3] = s4.w;
    }
#pragma unroll
    for (int n = 0; n < 4; ++n)
        sqj[n] = sqc[tj * TILE + wc * 64 + n * 16 + lr];

    float psum = 0.f;
#pragma unroll
    for (int m = 0; m < 4; ++m)
#pragma unroll
        for (int n = 0; n < 4; ++n) {
#pragma unroll
            for (int r = 0; r < 4; ++r) {
                // C/D layout (m89-verified): col = lane&15, row = (lane>>4)*4 + r
                float d2 = sqi[m][r] + sqj[n] - 2.0f * acc[m][n][r];
                float t1 = __builtin_amdgcn_exp2f(d2 * ci);
                float t2 = t1 * t1, t4 = t2 * t2, t8 = t4 * t4, t16 = t8 * t8;
                psum += ((t1 + t2) + (t4 + t8)) + t16;
            }
        }

#pragma unroll
    for (int off = 32; off > 0; off >>= 1) psum += __shfl_down(psum, off);
    float* red = reinterpret_cast<float*>(&lA[0][0]);
    __syncthreads();                              // all LDS reads done before reuse
    if (lane == 0) red[wid] = psum;
    __syncthreads();
    if (t == 0) {
        float sblk = red[0] + red[1] + red[2] + red[3];
        partial[blk] = sblk;
    }
}

// ---------------- final: deterministic combine of 32x36 tile sums --------------------
__global__ __launch_bounds__(64) void k_final(const float* __restrict__ partial,
                                              float* __restrict__ out) {
    int lane = threadIdx.x;
    double r = 0.0;
    if (lane < CCH) {
        const float* pp = partial + (size_t)lane * NPAIRS;
        double s = 0.0;
        for (int q = 0; q < NPAIRS; ++q) {
            int ti = PI_[q], tj = PJ_[q];
            double w = (ti == tj) ? 1.0 : 2.0;               // off-diag pair counted twice
            double sgn = ((ti < 4) == (tj < 4)) ? 1.0 : -1.0; // XX/YY : +, cross : -
            s += sgn * w * (double)pp[q];
        }
        r = s / ((double)BATCH * (double)BATCH);
    }
    for (int off = 16; off > 0; off >>= 1) r += __shfl_down(r, off);
    if (lane == 0) out[0] = (float)(r / (double)CCH);
}

extern "C" void kernel_launch(void* const* d_in, const int* in_sizes, int n_in,
                              void* d_out, int out_size, void* d_ws, size_t ws_size,
                              hipStream_t stream) {
    const float* src = (const float*)d_in[0];
    const float* tgt = (const float*)d_in[1];
    float* out = (float*)d_out;
    char* ws = (char*)d_ws;

    const size_t OFF_BF   = 0;                                       // 50,331,648 B
    const size_t OFF_SQ   = (size_t)CCH * NROW * DDIM * 2;           // +131,072 B
    const size_t OFF_CP   = OFF_SQ + (size_t)CCH * NROW * 4;         // +786,432 B
    const size_t OFF_BWC  = OFF_CP + (size_t)CCH * 8 * DDIM * 4;     // +128 B
    const size_t OFF_PART = OFF_BWC + (size_t)CCH * 4;               // +4,608 B

    u16*   bfbuf   = (u16*)(ws + OFF_BF);
    float* sq      = (float*)(ws + OFF_SQ);
    float* colpart = (float*)(ws + OFF_CP);
    float* bwc     = (float*)(ws + OFF_BWC);
    float* partial = (float*)(ws + OFF_PART);

    k_prep<<<CCH * NROW / 16, 256, 0, stream>>>(src, tgt, bfbuf, sq);
    k_colsum<<<CCH * 8, 256, 0, stream>>>(bfbuf, colpart);
    k_bw<<<CCH, 256, 0, stream>>>(sq, colpart, bwc);
    k_mmd<<<CCH * NPAIRS, 256, 0, stream>>>(bfbuf, sq, bwc, partial);
    k_final<<<1, 64, 0, stream>>>(partial, out);
}

// Round 9
// 69.193 us; speedup vs baseline: 1.5123x; 1.2921x over previous
//
#include <hip/hip_runtime.h>
#include <stdint.h>

#define CCH 32
#define BATCH 512
#define NROW 1024   // 2*BATCH
#define DDIM 768
#define TILE 128
#define NPAIRS 36   // upper-tri tile pairs of 8x8
#define BK 32
#define NSTEP (DDIM / BK)   // 24

typedef unsigned short u16;
typedef __attribute__((ext_vector_type(8))) short short8v;   // 8 bf16 (4 VGPRs)
typedef __attribute__((ext_vector_type(4))) float f32x4;     // MFMA acc

__device__ __forceinline__ u16 f2bf_rne(float x) {
    uint32_t u = __float_as_uint(x);
    u += 0x7FFFu + ((u >> 16) & 1u);
    return (u16)(u >> 16);
}
__device__ __forceinline__ float bf2f(u16 h) {
    return __uint_as_float(((uint32_t)h) << 16);
}

__device__ __forceinline__ void gload_lds16(const u16* g, u16* l) {
    // async global->LDS, 16B per lane; LDS dest = wave-uniform base + lane*16
    __builtin_amdgcn_global_load_lds(
        (const __attribute__((address_space(1))) unsigned int*)(g),
        (__attribute__((address_space(3))) unsigned int*)(l),
        16, 0, 0);
}

__constant__ int PI_[NPAIRS] = {0,0,0,0,0,0,0,0, 1,1,1,1,1,1,1, 2,2,2,2,2,2,
                                3,3,3,3,3, 4,4,4,4, 5,5,5, 6,6, 7};
__constant__ int PJ_[NPAIRS] = {0,1,2,3,4,5,6,7, 1,2,3,4,5,6,7, 2,3,4,5,6,7,
                                3,4,5,6,7, 4,5,6,7, 5,6,7, 6,7, 7};

// ---------------- prep: fp32 -> bf16 + row norms + FUSED column-sum partials ---------
// 1024 threads / 16 waves / 64 rows (one channel); 12 float4 loads forced in flight
// via asm memory fence (loads cannot sink across a clobber). Emits one bf16 colsum
// partial vector per block -> kills the separate 48MB-re-read k_colsum kernel.
__global__ __launch_bounds__(1024, 4) void k_prep(const float* __restrict__ src,
                                                  const float* __restrict__ tgt,
                                                  u16* __restrict__ bfbuf,
                                                  float* __restrict__ sq,
                                                  u16* __restrict__ cp2) {
    __shared__ float cpl[16][768];               // 48 KB
    int wid = threadIdx.x >> 6, lane = threadIdx.x & 63;
    int rbase = blockIdx.x * 64 + wid * 4;       // 64 rows/block; grid 512
    const float* rp[4];
#pragma unroll
    for (int r = 0; r < 4; ++r) {
        int row = rbase + r;
        int c = row >> 10, i = row & 1023;
        rp[r] = (i < BATCH) ? (src + ((size_t)i * CCH + c) * DDIM)
                            : (tgt + ((size_t)(i - BATCH) * CCH + c) * DDIM);
    }
    float4 v[4][3];
#pragma unroll
    for (int r = 0; r < 4; ++r)
#pragma unroll
        for (int j = 0; j < 3; ++j)
            v[r][j] = *(reinterpret_cast<const float4*>(rp[r]) + lane + j * 64);
    asm volatile("" ::: "memory");               // fence: all 12 loads issued above

    float cp[3][4];
#pragma unroll
    for (int j = 0; j < 3; ++j)
#pragma unroll
        for (int e = 0; e < 4; ++e) cp[j][e] = 0.f;

#pragma unroll
    for (int r = 0; r < 4; ++r) {
        u16* orow = bfbuf + (size_t)(rbase + r) * DDIM;
        float ss = 0.f;
#pragma unroll
        for (int j = 0; j < 3; ++j) {
            float4 w = v[r][j];
            u16 h0 = f2bf_rne(w.x), h1 = f2bf_rne(w.y), h2 = f2bf_rne(w.z), h3 = f2bf_rne(w.w);
            float f0 = bf2f(h0), f1 = bf2f(h1), f2 = bf2f(h2), f3 = bf2f(h3);
            ss += f0 * f0 + f1 * f1 + f2 * f2 + f3 * f3;
            cp[j][0] += f0; cp[j][1] += f1; cp[j][2] += f2; cp[j][3] += f3;
            ushort4 hv; hv.x = h0; hv.y = h1; hv.z = h2; hv.w = h3;
            *reinterpret_cast<ushort4*>(orow + (size_t)(lane + j * 64) * 4) = hv;
        }
#pragma unroll
        for (int off = 32; off > 0; off >>= 1) ss += __shfl_down(ss, off);
        if (lane == 0) sq[rbase + r] = ss;
    }

    // column-sum partials: lane owns cols j*256 + 4*lane + e (summed over its 4 rows)
#pragma unroll
    for (int j = 0; j < 3; ++j) {
        float4 w; w.x = cp[j][0]; w.y = cp[j][1]; w.z = cp[j][2]; w.w = cp[j][3];
        *reinterpret_cast<float4*>(&cpl[wid][j * 256 + lane * 4]) = w;
    }
    __syncthreads();
    int t = threadIdx.x;
    if (t < 768) {
        float s = 0.f;
#pragma unroll
        for (int w = 0; w < 16; ++w) s += cpl[w][t];
        cp2[(size_t)blockIdx.x * 768 + t] = f2bf_rne(s);   // bf16 partial: err ~1e-7 rel
    }
}

// ---------------- bandwidth: sum(d2) = 2n*sum(sq) - 2*||colsum||^2 -------------------
__global__ __launch_bounds__(256) void k_bw(const float* __restrict__ sq,
                                            const u16* __restrict__ cp2,
                                            float* __restrict__ bwc) {
    int c = blockIdx.x, t = threadIdx.x;
    const float* sqc = sq + (size_t)c * NROW;
    float s = sqc[t] + sqc[t + 256] + sqc[t + 512] + sqc[t + 768];
    const u16* cpc = cp2 + (size_t)c * 16 * 768;   // 16 blocks per channel
    float s2 = 0.f;
#pragma unroll
    for (int j = 0; j < 3; ++j) {
        int d = t + j * 256;
        float cs = 0.f;
#pragma unroll
        for (int b = 0; b < 16; ++b) cs += bf2f(cpc[(size_t)b * 768 + d]);
        s2 += cs * cs;
    }
    __shared__ float redA[256], redB[256];
    redA[t] = s; redB[t] = s2;
    __syncthreads();
    for (int k = 128; k > 0; k >>= 1) {
        if (t < k) { redA[t] += redA[t + k]; redB[t] += redB[t + k]; }
        __syncthreads();
    }
    if (t == 0) {
        double sumd2 = 2.0 * (double)NROW * (double)redA[0] - 2.0 * (double)redB[0];
        double bw = sumd2 / ((double)NROW * (double)NROW - (double)NROW) / 4.0; // /2^(5//2)
        bwc[c] = (float)(-1.4426950408889634 / (16.0 * bw));  // exp2 scale, largest bw
    }
}

// ---------------- main: R5-proven 3-buffer 1-barrier pipeline, unrolled --------------
__global__ __launch_bounds__(256, 3) void k_mmd(const u16* __restrict__ bfbuf,
                                                const float* __restrict__ sq,
                                                const float* __restrict__ bwc,
                                                float* __restrict__ partial) {
    // bijective XCD swizzle: 1152 = 8 * 144 (4 channels contiguous per XCD)
    int orig = blockIdx.x;
    int blk = (orig & 7) * 144 + (orig >> 3);
    int c = blk / NPAIRS, p = blk - c * NPAIRS;
    int ti = PI_[p], tj = PJ_[p];
    const u16* Ab = bfbuf + ((size_t)c * NROW + (size_t)ti * TILE) * DDIM;
    const u16* Bb = bfbuf + ((size_t)c * NROW + (size_t)tj * TILE) * DDIM;

    __shared__ __align__(16) u16 lA[3][TILE * BK];   // 3 x 8 KB
    __shared__ __align__(16) u16 lB[3][TILE * BK];   // 3 x 8 KB  (48 KB total)

    int t = threadIdx.x;
    int wid = t >> 6, lane = t & 63;
    int lr = lane & 15, kg = lane >> 4;
    int wr = wid >> 1, wc = wid & 1;              // 2x2 wave grid; wave owns 64x64

    // per-lane invariant staging geometry (hoisted):
    int g0 = t, row0 = g0 >> 2, kc0 = ((g0 & 3) ^ ((row0 >> 1) & 3)) * 8;
    int g1 = t + 256, row1 = g1 >> 2, kc1 = ((g1 & 3) ^ ((row1 >> 1) & 3)) * 8;
    const u16* gA0 = Ab + (size_t)row0 * DDIM + kc0;
    const u16* gA1 = Ab + (size_t)row1 * DDIM + kc1;
    const u16* gB0 = Bb + (size_t)row0 * DDIM + kc0;
    const u16* gB1 = Bb + (size_t)row1 * DDIM + kc1;

    auto STAGE = [&](int buf, int k0) {
        gload_lds16(gA0 + k0, &lA[buf][(size_t)(wid * 64) * 8]);
        gload_lds16(gB0 + k0, &lB[buf][(size_t)(wid * 64) * 8]);
        gload_lds16(gA1 + k0, &lA[buf][(size_t)(wid * 64 + 256) * 8]);
        gload_lds16(gB1 + k0, &lB[buf][(size_t)(wid * 64 + 256) * 8]);
    };

    f32x4 acc[4][4];
#pragma unroll
    for (int m = 0; m < 4; ++m)
#pragma unroll
        for (int n = 0; n < 4; ++n) acc[m][n] = f32x4{0.f, 0.f, 0.f, 0.f};

    // swizzled read slot (proven 0-conflict): depends only on lr
    int ks = (kg ^ ((lr >> 1) & 3)) * 8;
    int raddrA = (wr * 64 + lr) * BK + ks;        // + m*16*BK
    int raddrB = (wc * 64 + lr) * BK + ks;        // + n*16*BK

    STAGE(0, 0);
    STAGE(1, BK);                                 // 8 stage-loads in flight

#pragma unroll
    for (int s = 0; s < NSTEP; ++s) {
        // drain everything older than stage(s+1): leaves exactly 4 outstanding
        if (s < NSTEP - 1) asm volatile("s_waitcnt vmcnt(4)" ::: "memory");
        else               asm volatile("s_waitcnt vmcnt(0)" ::: "memory");
        asm volatile("s_barrier" ::: "memory");   // all waves: cur tile resident
        if (s + 2 < NSTEP) STAGE((s + 2) % 3, (s + 2) * BK);  // static after unroll

        const int cur = s % 3;                    // compile-time constant per copy
        short8v af[4], bf[4];
#pragma unroll
        for (int m = 0; m < 4; ++m)
            af[m] = *reinterpret_cast<const short8v*>(&lA[cur][raddrA + m * 16 * BK]);
#pragma unroll
        for (int n = 0; n < 4; ++n)
            bf[n] = *reinterpret_cast<const short8v*>(&lB[cur][raddrB + n * 16 * BK]);
#pragma unroll
        for (int m = 0; m < 4; ++m)
#pragma unroll
            for (int n = 0; n < 4; ++n)
                acc[m][n] = __builtin_amdgcn_mfma_f32_16x16x32_bf16(af[m], bf[n], acc[m][n], 0, 0, 0);
        // no trailing barrier: 3-buffer rotation, writer targets buf two steps ahead
    }

    // epilogue: d2 -> sum_k exp(-d2/bw_k) via t + t^2 + t^4 + t^8 + t^16
    float ci = bwc[c];                            // -log2(e)/(16*bw)
    const float* sqc = sq + (size_t)c * NROW;
    float sqi[4][4], sqj[4];
#pragma unroll
    for (int m = 0; m < 4; ++m) {
        float4 s4 = *reinterpret_cast<const float4*>(&sqc[ti * TILE + wr * 64 + m * 16 + kg * 4]);
        sqi[m][0] = s4.x; sqi[m][1] = s4.y; sqi[m][2] = s4.z; sqi[m][3] = s4.w;
    }
#pragma unroll
    for (int n = 0; n < 4; ++n)
        sqj[n] = sqc[tj * TILE + wc * 64 + n * 16 + lr];

    float psum = 0.f;
#pragma unroll
    for (int m = 0; m < 4; ++m)
#pragma unroll
        for (int n = 0; n < 4; ++n) {
#pragma unroll
            for (int r = 0; r < 4; ++r) {
                // C/D layout (m89-verified): col = lane&15, row = (lane>>4)*4 + r
                float d2 = sqi[m][r] + sqj[n] - 2.0f * acc[m][n][r];
                float t1 = __builtin_amdgcn_exp2f(d2 * ci);
                float t2 = t1 * t1, t4 = t2 * t2, t8 = t4 * t4, t16 = t8 * t8;
                psum += ((t1 + t2) + (t4 + t8)) + t16;
            }
        }

#pragma unroll
    for (int off = 32; off > 0; off >>= 1) psum += __shfl_down(psum, off);
    float* red = reinterpret_cast<float*>(&lA[0][0]);
    __syncthreads();                              // all LDS reads done before reuse
    if (lane == 0) red[wid] = psum;
    __syncthreads();
    if (t == 0) {
        float sblk = red[0] + red[1] + red[2] + red[3];
        partial[blk] = sblk;
    }
}

// ---------------- final: deterministic combine of 32x36 tile sums --------------------
__global__ __launch_bounds__(64) void k_final(const float* __restrict__ partial,
                                              float* __restrict__ out) {
    int lane = threadIdx.x;
    double r = 0.0;
    if (lane < CCH) {
        const float* pp = partial + (size_t)lane * NPAIRS;
        double s = 0.0;
        for (int q = 0; q < NPAIRS; ++q) {
            int ti = PI_[q], tj = PJ_[q];
            double w = (ti == tj) ? 1.0 : 2.0;               // off-diag pair counted twice
            double sgn = ((ti < 4) == (tj < 4)) ? 1.0 : -1.0; // XX/YY : +, cross : -
            s += sgn * w * (double)pp[q];
        }
        r = s / ((double)BATCH * (double)BATCH);
    }
    for (int off = 16; off > 0; off >>= 1) r += __shfl_down(r, off);
    if (lane == 0) out[0] = (float)(r / (double)CCH);
}

extern "C" void kernel_launch(void* const* d_in, const int* in_sizes, int n_in,
                              void* d_out, int out_size, void* d_ws, size_t ws_size,
                              hipStream_t stream) {
    const float* src = (const float*)d_in[0];
    const float* tgt = (const float*)d_in[1];
    float* out = (float*)d_out;
    char* ws = (char*)d_ws;

    const size_t OFF_BF   = 0;                                       // 50,331,648 B
    const size_t OFF_SQ   = (size_t)CCH * NROW * DDIM * 2;           // +131,072 B
    const size_t OFF_CP   = OFF_SQ + (size_t)CCH * NROW * 4;         // +786,432 B (u16 512x768)
    const size_t OFF_BWC  = OFF_CP + (size_t)512 * 768 * 2;          // +128 B
    const size_t OFF_PART = OFF_BWC + (size_t)CCH * 4;               // +4,608 B

    u16*   bfbuf   = (u16*)(ws + OFF_BF);
    float* sq      = (float*)(ws + OFF_SQ);
    u16*   cp2     = (u16*)(ws + OFF_CP);
    float* bwc     = (float*)(ws + OFF_BWC);
    float* partial = (float*)(ws + OFF_PART);

    k_prep<<<CCH * NROW / 64, 1024, 0, stream>>>(src, tgt, bfbuf, sq, cp2);
    k_bw<<<CCH, 256, 0, stream>>>(sq, cp2, bwc);
    k_mmd<<<CCH * NPAIRS, 256, 0, stream>>>(bfbuf, sq, bwc, partial);
    k_final<<<1, 64, 0, stream>>>(partial, out);
}